// Round 9
// baseline (164.219 us; speedup 1.0000x reference)
//
#include <hip/hip_runtime.h>

// ---------------- problem constants ----------------
#define BM   8192      // B*M
#define NN1  16384
#define NN2  8192
#define NN3  4096
#define NB   80        // y bins, width 1.0
#define TSZ  768       // staged candidates per tile (12 KB)
#define QCAP 512       // hit queue capacity (mean ~100/set/block)

// ---------------- workspace layout (float element offsets) ----------------
#define OFF_LRS   0            // 8192 float4 y-sorted per batch, w=orig p
#define OFF_S1    32768        // sorted HR1, w=orig j in batch
#define OFF_S2    163840
#define OFF_S3    229376
#define OFF_F1    262144       // 2*16384*32 f32, orig-indexed
#define OFF_F2    1310720
#define OFF_F3    1835008
#define OFF_START 2097152      // int[8*81] (pad 1024)
#define OFF_WP    2098176      // 160*64 BN-folded w_out
#define OFF_SHIFT 2108416      // 64
#define WS_FLOATS 2108480      // ~8.4 MB

// ---------------- kernel 1: per-table sort blocks + F precompute + BN fold ----------------
// blocks 0..7: fully self-contained counting sort of one (set,batch) table
//              (LDS hist -> shfl prefix -> LDS-cursor scatter). No cross-block deps.
// blocks 8.. : flat elementwise F / BN sections.
__global__ __launch_bounds__(256) void kprep(
    const int* __restrict__ lr_idx, const int* __restrict__ h1i,
    const int* __restrict__ h2i, const int* __restrict__ h3i,
    const float* __restrict__ f1, const float* __restrict__ f2, const float* __restrict__ f3,
    const float* __restrict__ w14, const float* __restrict__ b14,
    const float* __restrict__ w24, const float* __restrict__ b24,
    const float* __restrict__ w34, const float* __restrict__ b34,
    const float* __restrict__ wout, const float* __restrict__ gam,
    const float* __restrict__ bet, const float* __restrict__ mean,
    const float* __restrict__ var, float* __restrict__ ws)
{
    __shared__ int hist[NB];
    __shared__ int stt[NB+1];
    __shared__ int cur[NB];
    int bx = blockIdx.x, tid = threadIdx.x;

    if (bx < 8) {   // ---- sort one table ----
        int t = bx;
        int N, ibase, dst4; const int* ip; float vsx, vsz; bool isLR = (t >= 6);
        if (t < 2)      { N=NN1; ip=h1i; ibase=(t&1)*NN1; vsx=0.05f; vsz=0.1f; dst4=OFF_S1/4+(t&1)*NN1; }
        else if (t < 4) { N=NN2; ip=h2i; ibase=(t&1)*NN2; vsx=0.1f;  vsz=0.2f; dst4=OFF_S2/4+(t&1)*NN2; }
        else if (t < 6) { N=NN3; ip=h3i; ibase=(t&1)*NN3; vsx=0.2f;  vsz=0.4f; dst4=OFF_S3/4+(t&1)*NN3; }
        else            { N=4096; ip=lr_idx; ibase=(t&1)*4096; vsx=0.4f; vsz=1.0f; dst4=OFF_LRS/4+(t&1)*4096; }

        if (tid < NB) hist[tid] = 0;
        __syncthreads();
        for (int e = tid; e < N; e += 256) {
            int iy = ip[(ibase+e)*3 + 1];
            float y = __fadd_rn(__fadd_rn(__fmul_rn((float)iy, vsx), -40.0f), __fmul_rn(0.5f, vsx));
            int k = min(NB-1, max(0, (int)floorf(y + 40.0f)));
            atomicAdd(&hist[k], 1);
        }
        __syncthreads();
        if (tid < 64) {
            int v = hist[tid];
            #pragma unroll
            for (int s = 1; s < 64; s <<= 1) { int u = __shfl_up(v, s); if (tid >= s) v += u; }
            int base64 = __shfl(v, 63);
            int v2 = (tid < 16) ? hist[64 + tid] : 0;
            #pragma unroll
            for (int s = 1; s < 16; s <<= 1) { int u = __shfl_up(v2, s); if (tid >= s) v2 += u; }
            if (tid == 0) stt[0] = 0;
            stt[1 + tid] = v;
            if (tid < 16) stt[65 + tid] = base64 + v2;
        }
        __syncthreads();
        if (tid < NB) cur[tid] = stt[tid];
        if (tid < NB+1) reinterpret_cast<int*>(ws)[OFF_START + t*81 + tid] = stt[tid];
        __syncthreads();
        for (int e = tid; e < N; e += 256) {
            int r3 = (ibase+e)*3;
            int iz = ip[r3], iy = ip[r3+1], ix = ip[r3+2];
            float4 v;
            v.x = __fadd_rn(__fadd_rn(__fmul_rn((float)ix, vsx),   0.0f), __fmul_rn(0.5f, vsx));
            v.y = __fadd_rn(__fadd_rn(__fmul_rn((float)iy, vsx), -40.0f), __fmul_rn(0.5f, vsx));
            v.z = __fadd_rn(__fadd_rn(__fmul_rn((float)iz, vsz),  -3.0f), __fmul_rn(0.5f, vsz));
            v.w = __int_as_float(isLR ? (ibase + e) : e);   // LR: global p; HR: j within batch
            int k = min(NB-1, max(0, (int)floorf(v.y + 40.0f)));
            int pos = atomicAdd(&cur[k], 1);
            reinterpret_cast<float4*>(ws)[dst4 + pos] = v;
        }
        return;
    }

    int e = (bx - 8) * 256 + tid;

    // F1: 4 channels/thread
    if (e < 262144) {
        int o2 = e & 7, jj = e >> 3;
        const float4* fv = reinterpret_cast<const float4*>(f1) + jj*4;
        const float4* w4 = reinterpret_cast<const float4*>(w14);
        float4 acc = reinterpret_cast<const float4*>(b14)[o2];
        float fr[16];
        #pragma unroll
        for (int c4 = 0; c4 < 4; ++c4) {
            float4 f = fv[c4];
            fr[c4*4] = f.x; fr[c4*4+1] = f.y; fr[c4*4+2] = f.z; fr[c4*4+3] = f.w;
        }
        #pragma unroll
        for (int c = 0; c < 16; ++c) {
            float4 w = w4[(3+c)*8 + o2];
            acc.x = fmaf(fr[c], w.x, acc.x); acc.y = fmaf(fr[c], w.y, acc.y);
            acc.z = fmaf(fr[c], w.z, acc.z); acc.w = fmaf(fr[c], w.w, acc.w);
        }
        reinterpret_cast<float4*>(ws + OFF_F1)[jj*8 + o2] = acc;
        return;
    }
    e -= 262144;
    if (e < 131072) {
        int o2 = e & 7, jj = e >> 3;
        const float4* fv = reinterpret_cast<const float4*>(f2) + jj*8;
        const float4* w4 = reinterpret_cast<const float4*>(w24);
        float4 acc = reinterpret_cast<const float4*>(b24)[o2];
        #pragma unroll
        for (int cc = 0; cc < 32; cc += 16) {
            float fr[16];
            #pragma unroll
            for (int c4 = 0; c4 < 4; ++c4) {
                float4 f = fv[cc/4 + c4];
                fr[c4*4] = f.x; fr[c4*4+1] = f.y; fr[c4*4+2] = f.z; fr[c4*4+3] = f.w;
            }
            #pragma unroll
            for (int c = 0; c < 16; ++c) {
                float4 w = w4[(3+cc+c)*8 + o2];
                acc.x = fmaf(fr[c], w.x, acc.x); acc.y = fmaf(fr[c], w.y, acc.y);
                acc.z = fmaf(fr[c], w.z, acc.z); acc.w = fmaf(fr[c], w.w, acc.w);
            }
        }
        reinterpret_cast<float4*>(ws + OFF_F2)[jj*8 + o2] = acc;
        return;
    }
    e -= 131072;
    if (e < 65536) {
        int o2 = e & 7, jj = e >> 3;
        const float4* fv = reinterpret_cast<const float4*>(f3) + jj*16;
        const float4* w4 = reinterpret_cast<const float4*>(w34);
        float4 acc = reinterpret_cast<const float4*>(b34)[o2];
        #pragma unroll
        for (int cc = 0; cc < 64; cc += 16) {
            float fr[16];
            #pragma unroll
            for (int c4 = 0; c4 < 4; ++c4) {
                float4 f = fv[cc/4 + c4];
                fr[c4*4] = f.x; fr[c4*4+1] = f.y; fr[c4*4+2] = f.z; fr[c4*4+3] = f.w;
            }
            #pragma unroll
            for (int c = 0; c < 16; ++c) {
                float4 w = w4[(3+cc+c)*8 + o2];
                acc.x = fmaf(fr[c], w.x, acc.x); acc.y = fmaf(fr[c], w.y, acc.y);
                acc.z = fmaf(fr[c], w.z, acc.z); acc.w = fmaf(fr[c], w.w, acc.w);
            }
        }
        reinterpret_cast<float4*>(ws + OFF_F3)[jj*8 + o2] = acc;
        return;
    }
    e -= 65536;

    if (e < 10240) {
        int o = e & 63;
        float sc = gam[o] * (1.0f / sqrtf(var[o] + 1e-3f));
        ws[OFF_WP + e] = wout[e] * sc;
    } else if (e < 10304) {
        int o = e - 10240;
        float sc = gam[o] * (1.0f / sqrtf(var[o] + 1e-3f));
        ws[OFF_SHIFT + o] = bet[o] - mean[o] * sc;
    }
}

// ---------------- kernel 2: fused pruned scan (3 sets) + concat + matmul + BN + ReLU ----------------
// Block (512 thr) = 32-point y-sorted group. Per set: stage window in LDS,
// half-wave candidate test (lanes 0-31 even, 32-63 odd), hit queue, wave-wide
// MLP into LDS acc, writeback (with j=0 fallback) into cat tile. Then 160x64
// matmul from LDS and scatter rows to out at original point indices.
__global__ __launch_bounds__(512) void kscan(
    float* __restrict__ ws, const float* __restrict__ lr_feat,
    const int* __restrict__ h1i, const int* __restrict__ h2i, const int* __restrict__ h3i,
    const float* __restrict__ w14, const float* __restrict__ w24, const float* __restrict__ w34,
    float* __restrict__ out)
{
    __shared__ float4 Sst[TSZ];
    __shared__ float  catS[32][160];
    __shared__ int    accS[32*33];
    __shared__ float  lrS[32*4];
    __shared__ float  wAll[288];
    __shared__ int    cntS[32];
    __shared__ int    porigS[32];
    __shared__ int    queue[QCAP];
    __shared__ int    qn;

    int pg = blockIdx.x;              // 0..255 (32-pt groups)
    int b  = pg >> 7;
    int tid = threadIdx.x, lane = tid & 63, half = lane >> 5, p = lane & 31, wv = tid >> 6;

    if (tid < 96)        wAll[tid]       = w14[tid];
    else if (tid < 192)  wAll[tid]       = w24[tid-96];
    else if (tid < 288)  wAll[tid-192+192] = w34[tid-192];
    for (int e = tid; e < 32*33; e += 512) accS[e] = 0;
    if (tid < 32) {
        float4 l = reinterpret_cast<const float4*>(ws + OFF_LRS)[pg*32 + tid];
        reinterpret_cast<float4*>(lrS)[tid] = l;
        porigS[tid] = __float_as_int(l.w);
        cntS[tid] = 0;
    }
    if (tid == 0) qn = 0;

    float4 lr = reinterpret_cast<const float4*>(ws + OFF_LRS)[pg*32 + p];
    float ymin = lr.y, ymax = lr.y;
    #pragma unroll
    for (int m = 1; m < 32; m <<= 1) {
        ymin = fminf(ymin, __shfl_xor(ymin, m));
        ymax = fmaxf(ymax, __shfl_xor(ymax, m));
    }
    int klo = max(0, (int)floorf(ymin - 1.001f + 40.0f));
    int khi = min(NB-1, (int)floorf(ymax + 1.001f + 40.0f));

    __syncthreads();

    // preload lr_feat rows into cat tile
    for (int e = tid; e < 2048; e += 512) {
        int i = e >> 6, c = e & 63;
        catS[i][c] = lr_feat[porigS[i]*64 + c];
    }

    #pragma unroll 1
    for (int s = 0; s < 3; ++s) {
        const int* hidx; int soff, Foff, N, wb; float vsx, vsz;
        if (s == 0)      { hidx=h1i; soff=OFF_S1; Foff=OFF_F1; N=NN1; vsx=0.05f; vsz=0.1f; wb=0; }
        else if (s == 1) { hidx=h2i; soff=OFF_S2; Foff=OFF_F2; N=NN2; vsx=0.1f;  vsz=0.2f; wb=96; }
        else             { hidx=h3i; soff=OFF_S3; Foff=OFF_F3; N=NN3; vsx=0.2f;  vsz=0.4f; wb=192; }

        const int* st = reinterpret_cast<const int*>(ws) + OFF_START + (s*2+b)*81;
        int j0 = st[klo], j1 = st[khi+1];
        const float4* S  = reinterpret_cast<const float4*>(ws + soff) + b*N;
        const float* Fb = ws + Foff + (size_t)b*N*32;

        for (int t0 = j0; t0 < j1; t0 += TSZ) {
            int tlen = min(TSZ, j1 - t0);
            __syncthreads();                     // Sst free + qn reset visible
            for (int e = tid; e < tlen; e += 512) Sst[e] = S[t0 + e];
            __syncthreads();

            int a   = (tlen * wv) >> 3;
            int bnd = (tlen * (wv+1)) >> 3;
            for (int j = a + half; j < bnd; j += 2) {
                float4 q = Sst[j];
                float dx = q.x - lr.x, dy = q.y - lr.y, dz = q.z - lr.z;
                float d2 = __fadd_rn(__fadd_rn(__fmul_rn(dx,dx), __fmul_rn(dy,dy)), __fmul_rn(dz,dz));
                if (d2 < 1.0f) {                 // exact np op order
                    cntS[p] = 1;                 // benign race
                    int pos = atomicAdd(&qn, 1);
                    if (pos < QCAP) queue[pos] = (j << 5) | p;
                }
            }
            __syncthreads();

            int nh = min(qn, QCAP);
            for (int e = tid; e < nh*32; e += 512) {
                int ent = queue[e >> 5], o = e & 31;
                int jl = ent >> 5, pp = ent & 31;
                float4 q = Sst[jl];
                float dx = q.x - lrS[pp*4], dy = q.y - lrS[pp*4+1], dz = q.z - lrS[pp*4+2];
                int jo = __float_as_int(q.w);
                float h = Fb[(size_t)jo*32 + o] + dx*wAll[wb+o] + dy*wAll[wb+32+o] + dz*wAll[wb+64+o];
                atomicMax(&accS[pp*33 + o], __float_as_int(h));
            }
            __syncthreads();
            if (tid == 0) qn = 0;
        }

        // fallback coords (orig j=0 of this set/batch)
        int i0 = b * N * 3;
        int hz = hidx[i0], hy = hidx[i0+1], hx = hidx[i0+2];
        float q0x = __fadd_rn(__fadd_rn(__fmul_rn((float)hx, vsx),   0.0f), __fmul_rn(0.5f, vsx));
        float q0y = __fadd_rn(__fadd_rn(__fmul_rn((float)hy, vsx), -40.0f), __fmul_rn(0.5f, vsx));
        float q0z = __fadd_rn(__fadd_rn(__fmul_rn((float)hz, vsz),  -3.0f), __fmul_rn(0.5f, vsz));

        for (int e = tid; e < 1024; e += 512) {
            int i = e >> 5, o = e & 31;
            float v;
            if (cntS[i]) v = __int_as_float(accS[i*33 + o]);
            else {
                float dx = q0x - lrS[i*4], dy = q0y - lrS[i*4+1], dz = q0z - lrS[i*4+2];
                v = fmaxf(Fb[o] + dx*wAll[wb+o] + dy*wAll[wb+32+o] + dz*wAll[wb+64+o], 0.f);
            }
            catS[i][64 + s*32 + o] = v;
        }
        __syncthreads();
        for (int e = tid; e < 32*33; e += 512) accS[e] = 0;
        if (tid < 32) cntS[tid] = 0;
        // next set's pre-staging barrier orders the zeroing before new pushes
    }
    __syncthreads();

    // matmul: wave wv -> points wv*4..wv*4+3
    float sh = ws[OFF_SHIFT + lane];
    float acc[4] = {sh, sh, sh, sh};
    const float* wp = ws + OFF_WP;
    #pragma unroll 2
    for (int c = 0; c < 160; c += 4) {
        float w0 = wp[(c+0)*64 + lane];
        float w1 = wp[(c+1)*64 + lane];
        float w2 = wp[(c+2)*64 + lane];
        float w3 = wp[(c+3)*64 + lane];
        #pragma unroll
        for (int pt = 0; pt < 4; ++pt) {
            float4 cv = *reinterpret_cast<const float4*>(&catS[wv*4 + pt][c]);
            acc[pt] = fmaf(cv.x, w0, acc[pt]);
            acc[pt] = fmaf(cv.y, w1, acc[pt]);
            acc[pt] = fmaf(cv.z, w2, acc[pt]);
            acc[pt] = fmaf(cv.w, w3, acc[pt]);
        }
    }
    #pragma unroll
    for (int pt = 0; pt < 4; ++pt)
        out[porigS[wv*4 + pt]*64 + lane] = fmaxf(acc[pt], 0.f);
}

// ---------------- host launcher ----------------
extern "C" void kernel_launch(void* const* d_in, const int* in_sizes, int n_in,
                              void* d_out, int out_size, void* d_ws, size_t ws_size,
                              hipStream_t stream) {
    const int*   lr_idx = (const int*)d_in[0];
    const int*   h1i    = (const int*)d_in[1];
    const int*   h2i    = (const int*)d_in[2];
    const int*   h3i    = (const int*)d_in[3];
    const float* lrf    = (const float*)d_in[4];
    const float* f1     = (const float*)d_in[5];
    const float* f2     = (const float*)d_in[6];
    const float* f3     = (const float*)d_in[7];
    const float* w14    = (const float*)d_in[8];
    const float* b14    = (const float*)d_in[9];
    const float* w24    = (const float*)d_in[10];
    const float* b24    = (const float*)d_in[11];
    const float* w34    = (const float*)d_in[12];
    const float* b34    = (const float*)d_in[13];
    const float* wout   = (const float*)d_in[14];
    const float* gam    = (const float*)d_in[15];
    const float* bet    = (const float*)d_in[16];
    const float* mean   = (const float*)d_in[17];
    const float* var    = (const float*)d_in[18];
    float* ws  = (float*)d_ws;
    float* out = (float*)d_out;

    if (ws_size < (size_t)WS_FLOATS * sizeof(float)) return;  // ~8.4 MB scratch

    // 8 sort blocks + 1833 flat blocks (F1 1024, F2 512, F3 256, BN 41)
    kprep<<<1841, 256, 0, stream>>>(lr_idx, h1i, h2i, h3i, f1, f2, f3,
                                    w14, b14, w24, b24, w34, b34,
                                    wout, gam, bet, mean, var, ws);
    // 256 blocks x 512 thr: 32-pt groups, 3 sets + final matmul fused
    kscan<<<256, 512, 0, stream>>>(ws, lrf, h1i, h2i, h3i, w14, w24, w34, out);
}

// Round 10
// 139.191 us; speedup vs baseline: 1.1798x; 1.1798x over previous
//
#include <hip/hip_runtime.h>

// ---------------- problem constants ----------------
#define BM   8192      // B*M
#define NN1  16384
#define NN2  8192
#define NN3  4096
#define NB   80        // y bins, width 1.0
#define NBLK 32        // sort chunks
#define CHUNK 2048     // 65536/NBLK
#define TSZ  768       // staged candidates per tile (12 KB)
#define QCAP 512       // hit queue capacity (mean ~60/tile, >20 sigma margin)

// ---------------- workspace layout (float element offsets) ----------------
#define OFF_LRS   0            // 8192 float4 y-sorted per batch, w=orig global p
#define OFF_S1    32768        // sorted HR1, w=orig j in batch
#define OFF_S2    163840
#define OFF_S3    229376
#define OFF_F1    262144       // 2*16384*32 f32, orig-indexed
#define OFF_F2    1310720
#define OFF_F3    1835008
#define OFF_PART  2097152      // int[32*640] per-chunk histograms
#define OFF_START 2117632      // int[648] (pad to 1024)
#define OFF_WP    2118656      // 160*64 BN-folded w_out
#define OFF_SHIFT 2128896      // 64
#define WS_FLOATS 2128960      // ~8.5 MB

// table ids: HR s*2+b -> 0..5 ; LR 6+b

// ---------------- kernel 1: chunk histograms + F precompute + BN fold ----------------
__global__ __launch_bounds__(256) void kprep(
    const int* __restrict__ lr_idx, const int* __restrict__ h1i,
    const int* __restrict__ h2i, const int* __restrict__ h3i,
    const float* __restrict__ f1, const float* __restrict__ f2, const float* __restrict__ f3,
    const float* __restrict__ w14, const float* __restrict__ b14,
    const float* __restrict__ w24, const float* __restrict__ b24,
    const float* __restrict__ w34, const float* __restrict__ b34,
    const float* __restrict__ wout, const float* __restrict__ gam,
    const float* __restrict__ bet, const float* __restrict__ mean,
    const float* __restrict__ var, float* __restrict__ ws)
{
    __shared__ int hist[640];
    int bx = blockIdx.x, tid = threadIdx.x;

    if (bx < NBLK) {   // ---- histogram of one 2048-item chunk ----
        for (int e = tid; e < 640; e += 256) hist[e] = 0;
        __syncthreads();
        int base_it = bx * CHUNK;
        for (int t = tid; t < CHUNK; t += 256) {
            int e = base_it + t;
            int T, iy; float vsx;
            if (e < 8192)            { T = 6 + (e>>12); iy = lr_idx[e*3+1]; vsx = 0.4f; }
            else { int r = e - 8192;
              if (r < 32768)         { int b = r>>14; T = b;   iy = h1i[r*3+1]; vsx = 0.05f; }
              else { r -= 32768;
                if (r < 16384)       { int b = r>>13; T = 2+b; iy = h2i[r*3+1]; vsx = 0.1f; }
                else { r -= 16384; int b = r>>12; T = 4+b; iy = h3i[r*3+1]; vsx = 0.2f; }
              }
            }
            float y = __fadd_rn(__fadd_rn(__fmul_rn((float)iy, vsx), -40.0f), __fmul_rn(0.5f, vsx));
            int k = min(NB-1, max(0, (int)floorf(y + 40.0f)));
            atomicAdd(&hist[T*80 + k], 1);
        }
        __syncthreads();
        for (int e = tid; e < 640; e += 256)
            reinterpret_cast<int*>(ws)[OFF_PART + bx*640 + e] = hist[e];
        return;
    }

    int e = (bx - NBLK) * 256 + tid;

    // F1: 4 channels/thread
    if (e < 262144) {
        int o2 = e & 7, jj = e >> 3;
        const float4* fv = reinterpret_cast<const float4*>(f1) + jj*4;
        const float4* w4 = reinterpret_cast<const float4*>(w14);
        float4 acc = reinterpret_cast<const float4*>(b14)[o2];
        float fr[16];
        #pragma unroll
        for (int c4 = 0; c4 < 4; ++c4) {
            float4 f = fv[c4];
            fr[c4*4] = f.x; fr[c4*4+1] = f.y; fr[c4*4+2] = f.z; fr[c4*4+3] = f.w;
        }
        #pragma unroll
        for (int c = 0; c < 16; ++c) {
            float4 w = w4[(3+c)*8 + o2];
            acc.x = fmaf(fr[c], w.x, acc.x); acc.y = fmaf(fr[c], w.y, acc.y);
            acc.z = fmaf(fr[c], w.z, acc.z); acc.w = fmaf(fr[c], w.w, acc.w);
        }
        reinterpret_cast<float4*>(ws + OFF_F1)[jj*8 + o2] = acc;
        return;
    }
    e -= 262144;
    if (e < 131072) {
        int o2 = e & 7, jj = e >> 3;
        const float4* fv = reinterpret_cast<const float4*>(f2) + jj*8;
        const float4* w4 = reinterpret_cast<const float4*>(w24);
        float4 acc = reinterpret_cast<const float4*>(b24)[o2];
        #pragma unroll
        for (int cc = 0; cc < 32; cc += 16) {
            float fr[16];
            #pragma unroll
            for (int c4 = 0; c4 < 4; ++c4) {
                float4 f = fv[cc/4 + c4];
                fr[c4*4] = f.x; fr[c4*4+1] = f.y; fr[c4*4+2] = f.z; fr[c4*4+3] = f.w;
            }
            #pragma unroll
            for (int c = 0; c < 16; ++c) {
                float4 w = w4[(3+cc+c)*8 + o2];
                acc.x = fmaf(fr[c], w.x, acc.x); acc.y = fmaf(fr[c], w.y, acc.y);
                acc.z = fmaf(fr[c], w.z, acc.z); acc.w = fmaf(fr[c], w.w, acc.w);
            }
        }
        reinterpret_cast<float4*>(ws + OFF_F2)[jj*8 + o2] = acc;
        return;
    }
    e -= 131072;
    if (e < 65536) {
        int o2 = e & 7, jj = e >> 3;
        const float4* fv = reinterpret_cast<const float4*>(f3) + jj*16;
        const float4* w4 = reinterpret_cast<const float4*>(w34);
        float4 acc = reinterpret_cast<const float4*>(b34)[o2];
        #pragma unroll
        for (int cc = 0; cc < 64; cc += 16) {
            float fr[16];
            #pragma unroll
            for (int c4 = 0; c4 < 4; ++c4) {
                float4 f = fv[cc/4 + c4];
                fr[c4*4] = f.x; fr[c4*4+1] = f.y; fr[c4*4+2] = f.z; fr[c4*4+3] = f.w;
            }
            #pragma unroll
            for (int c = 0; c < 16; ++c) {
                float4 w = w4[(3+cc+c)*8 + o2];
                acc.x = fmaf(fr[c], w.x, acc.x); acc.y = fmaf(fr[c], w.y, acc.y);
                acc.z = fmaf(fr[c], w.z, acc.z); acc.w = fmaf(fr[c], w.w, acc.w);
            }
        }
        reinterpret_cast<float4*>(ws + OFF_F3)[jj*8 + o2] = acc;
        return;
    }
    e -= 65536;

    if (e < 10240) {
        int o = e & 63;
        float sc = gam[o] * (1.0f / sqrtf(var[o] + 1e-3f));
        ws[OFF_WP + e] = wout[e] * sc;
    } else if (e < 10304) {
        int o = e - 10240;
        float sc = gam[o] * (1.0f / sqrtf(var[o] + 1e-3f));
        ws[OFF_SHIFT + o] = bet[o] - mean[o] * sc;
    }
}

// ---------------- kernel 2: fused prefix + scatter (32 blocks derive own cursors) ----------------
__global__ __launch_bounds__(1024) void ksort(
    const int* __restrict__ lr_idx, const int* __restrict__ h1i,
    const int* __restrict__ h2i, const int* __restrict__ h3i,
    float* __restrict__ ws)
{
    __shared__ int totS[640];
    __shared__ int stt[648];
    __shared__ int cur[640];
    int t = threadIdx.x, bx = blockIdx.x;
    int* wsi = reinterpret_cast<int*>(ws);

    int tot = 0, mypre = 0;
    if (t < 640) {
        #pragma unroll
        for (int b = 0; b < NBLK; ++b) {
            int p = wsi[OFF_PART + b*640 + t];
            tot += p;
            if (b < bx) mypre += p;
        }
        totS[t] = tot;
    }
    __syncthreads();
    int wid = t >> 6, lane = t & 63;
    if (wid < 8) {
        int v = totS[wid*80 + lane];
        #pragma unroll
        for (int s = 1; s < 64; s <<= 1) { int u = __shfl_up(v, s); if (lane >= s) v += u; }
        int base64 = __shfl(v, 63);
        int v2 = (lane < 16) ? totS[wid*80 + 64 + lane] : 0;
        #pragma unroll
        for (int s = 1; s < 16; s <<= 1) { int u = __shfl_up(v2, s); if (lane >= s) v2 += u; }
        if (lane == 0) stt[wid*81] = 0;
        stt[wid*81 + 1 + lane] = v;
        if (lane < 16) stt[wid*81 + 65 + lane] = base64 + v2;
    }
    __syncthreads();
    if (bx == 0 && t < 648) wsi[OFF_START + t] = stt[t];
    if (t < 640) cur[t] = stt[(t/80)*81 + (t%80)] + mypre;
    __syncthreads();

    int base_it = bx * CHUNK;
    for (int tt = t; tt < CHUNK; tt += 1024) {
        int e = base_it + tt;
        int T, w, dst4, r3; const int* ip; float vsx, vsz;
        if (e < 8192) {
            int b = e >> 12; T = 6+b; ip = lr_idx; r3 = e*3; vsx = 0.4f; vsz = 1.0f;
            w = e; dst4 = OFF_LRS/4 + b*4096;
        } else { int r = e - 8192;
          if (r < 32768) { int b = r>>14; T = b;   ip = h1i; r3 = r*3; vsx = 0.05f; vsz = 0.1f; w = r - b*NN1; dst4 = OFF_S1/4 + b*NN1; }
          else { r -= 32768;
            if (r < 16384) { int b = r>>13; T = 2+b; ip = h2i; r3 = r*3; vsx = 0.1f; vsz = 0.2f; w = r - b*NN2; dst4 = OFF_S2/4 + b*NN2; }
            else { r -= 16384; int b = r>>12; T = 4+b; ip = h3i; r3 = r*3; vsx = 0.2f; vsz = 0.4f; w = r - b*NN3; dst4 = OFF_S3/4 + b*NN3; }
          }
        }
        int iz = ip[r3], iy = ip[r3+1], ix = ip[r3+2];
        float4 v;
        v.x = __fadd_rn(__fadd_rn(__fmul_rn((float)ix, vsx),   0.0f), __fmul_rn(0.5f, vsx));
        v.y = __fadd_rn(__fadd_rn(__fmul_rn((float)iy, vsx), -40.0f), __fmul_rn(0.5f, vsx));
        v.z = __fadd_rn(__fadd_rn(__fmul_rn((float)iz, vsz),  -3.0f), __fmul_rn(0.5f, vsz));
        v.w = __int_as_float(w);
        int k = min(NB-1, max(0, (int)floorf(v.y + 40.0f)));
        int pos = atomicAdd(&cur[T*80 + k], 1);
        reinterpret_cast<float4*>(ws)[dst4 + pos] = v;
    }
}

// ---------------- kernel 3: fused pruned scan (3 sets) + concat + matmul + BN + ReLU ----------------
// Block (512 thr) = 32-point y-sorted group. Per set: stage window in LDS,
// half-wave candidate test, hit queue, wave-wide MLP into LDS acc, writeback
// (with j=0 fallback) into cat tile. Then 160x64 matmul, scatter rows to out.
__global__ __launch_bounds__(512) void kmain(
    float* __restrict__ ws, const float* __restrict__ lr_feat,
    const int* __restrict__ h1i, const int* __restrict__ h2i, const int* __restrict__ h3i,
    const float* __restrict__ w14, const float* __restrict__ w24, const float* __restrict__ w34,
    float* __restrict__ out)
{
    __shared__ float4 Sst[TSZ];
    __shared__ float  catS[32][160];
    __shared__ int    accS[32*33];
    __shared__ float  lrS[32*4];
    __shared__ float  wAll[288];
    __shared__ int    cntS[32];
    __shared__ int    porigS[32];
    __shared__ int    queue[QCAP];
    __shared__ int    qn;

    int pg = blockIdx.x;              // 0..255 (32-pt groups)
    int b  = pg >> 7;
    int tid = threadIdx.x, lane = tid & 63, half = lane >> 5, p = lane & 31, wv = tid >> 6;

    if (tid < 96)        wAll[tid] = w14[tid];
    else if (tid < 192)  wAll[tid] = w24[tid-96];
    else if (tid < 288)  wAll[tid] = w34[tid-192];
    for (int e = tid; e < 32*33; e += 512) accS[e] = 0;
    if (tid < 32) {
        float4 l = reinterpret_cast<const float4*>(ws + OFF_LRS)[pg*32 + tid];
        reinterpret_cast<float4*>(lrS)[tid] = l;
        porigS[tid] = __float_as_int(l.w);
        cntS[tid] = 0;
    }
    if (tid == 0) qn = 0;

    float4 lr = reinterpret_cast<const float4*>(ws + OFF_LRS)[pg*32 + p];
    float ymin = lr.y, ymax = lr.y;
    #pragma unroll
    for (int m = 1; m < 32; m <<= 1) {
        ymin = fminf(ymin, __shfl_xor(ymin, m));
        ymax = fmaxf(ymax, __shfl_xor(ymax, m));
    }
    int klo = max(0, (int)floorf(ymin - 1.001f + 40.0f));
    int khi = min(NB-1, (int)floorf(ymax + 1.001f + 40.0f));

    __syncthreads();

    // preload lr_feat rows into cat tile
    for (int e = tid; e < 2048; e += 512) {
        int i = e >> 6, c = e & 63;
        catS[i][c] = lr_feat[porigS[i]*64 + c];
    }

    #pragma unroll 1
    for (int s = 0; s < 3; ++s) {
        const int* hidx; int soff, Foff, N, wb; float vsx, vsz;
        if (s == 0)      { hidx=h1i; soff=OFF_S1; Foff=OFF_F1; N=NN1; vsx=0.05f; vsz=0.1f; wb=0; }
        else if (s == 1) { hidx=h2i; soff=OFF_S2; Foff=OFF_F2; N=NN2; vsx=0.1f;  vsz=0.2f; wb=96; }
        else             { hidx=h3i; soff=OFF_S3; Foff=OFF_F3; N=NN3; vsx=0.2f;  vsz=0.4f; wb=192; }

        const int* st = reinterpret_cast<const int*>(ws) + OFF_START + (s*2+b)*81;
        int j0 = st[klo], j1 = st[khi+1];
        const float4* S  = reinterpret_cast<const float4*>(ws + soff) + b*N;
        const float* Fb = ws + Foff + (size_t)b*N*32;

        for (int t0 = j0; t0 < j1; t0 += TSZ) {
            int tlen = min(TSZ, j1 - t0);
            __syncthreads();                     // Sst free + qn reset visible
            for (int e = tid; e < tlen; e += 512) Sst[e] = S[t0 + e];
            __syncthreads();

            int a   = (tlen * wv) >> 3;
            int bnd = (tlen * (wv+1)) >> 3;
            for (int j = a + half; j < bnd; j += 2) {
                float4 q = Sst[j];
                float dx = q.x - lr.x, dy = q.y - lr.y, dz = q.z - lr.z;
                float d2 = __fadd_rn(__fadd_rn(__fmul_rn(dx,dx), __fmul_rn(dy,dy)), __fmul_rn(dz,dz));
                if (d2 < 1.0f) {                 // exact np op order
                    cntS[p] = 1;                 // benign race
                    int pos = atomicAdd(&qn, 1);
                    if (pos < QCAP) queue[pos] = (j << 5) | p;
                }
            }
            __syncthreads();

            int nh = min(qn, QCAP);
            for (int e = tid; e < nh*32; e += 512) {
                int ent = queue[e >> 5], o = e & 31;
                int jl = ent >> 5, pp = ent & 31;
                float4 q = Sst[jl];
                float dx = q.x - lrS[pp*4], dy = q.y - lrS[pp*4+1], dz = q.z - lrS[pp*4+2];
                int jo = __float_as_int(q.w);
                float h = Fb[(size_t)jo*32 + o] + dx*wAll[wb+o] + dy*wAll[wb+32+o] + dz*wAll[wb+64+o];
                atomicMax(&accS[pp*33 + o], __float_as_int(h));
            }
            __syncthreads();
            if (tid == 0) qn = 0;
        }

        // fallback coords (orig j=0 of this set/batch)
        int i0 = b * N * 3;
        int hz = hidx[i0], hy = hidx[i0+1], hx = hidx[i0+2];
        float q0x = __fadd_rn(__fadd_rn(__fmul_rn((float)hx, vsx),   0.0f), __fmul_rn(0.5f, vsx));
        float q0y = __fadd_rn(__fadd_rn(__fmul_rn((float)hy, vsx), -40.0f), __fmul_rn(0.5f, vsx));
        float q0z = __fadd_rn(__fadd_rn(__fmul_rn((float)hz, vsz),  -3.0f), __fmul_rn(0.5f, vsz));

        for (int e = tid; e < 1024; e += 512) {
            int i = e >> 5, o = e & 31;
            float v;
            if (cntS[i]) v = __int_as_float(accS[i*33 + o]);
            else {
                float dx = q0x - lrS[i*4], dy = q0y - lrS[i*4+1], dz = q0z - lrS[i*4+2];
                v = fmaxf(Fb[o] + dx*wAll[wb+o] + dy*wAll[wb+32+o] + dz*wAll[wb+64+o], 0.f);
            }
            catS[i][64 + s*32 + o] = v;
        }
        __syncthreads();
        for (int e = tid; e < 32*33; e += 512) accS[e] = 0;
        if (tid < 32) cntS[tid] = 0;
        // next set's pre-staging barrier orders the zeroing before new pushes
    }
    __syncthreads();

    // matmul: wave wv -> points wv*4..wv*4+3
    float sh = ws[OFF_SHIFT + lane];
    float acc[4] = {sh, sh, sh, sh};
    const float* wp = ws + OFF_WP;
    #pragma unroll 2
    for (int c = 0; c < 160; c += 4) {
        float w0 = wp[(c+0)*64 + lane];
        float w1 = wp[(c+1)*64 + lane];
        float w2 = wp[(c+2)*64 + lane];
        float w3 = wp[(c+3)*64 + lane];
        #pragma unroll
        for (int pt = 0; pt < 4; ++pt) {
            float4 cv = *reinterpret_cast<const float4*>(&catS[wv*4 + pt][c]);
            acc[pt] = fmaf(cv.x, w0, acc[pt]);
            acc[pt] = fmaf(cv.y, w1, acc[pt]);
            acc[pt] = fmaf(cv.z, w2, acc[pt]);
            acc[pt] = fmaf(cv.w, w3, acc[pt]);
        }
    }
    #pragma unroll
    for (int pt = 0; pt < 4; ++pt)
        out[porigS[wv*4 + pt]*64 + lane] = fmaxf(acc[pt], 0.f);
}

// ---------------- host launcher ----------------
extern "C" void kernel_launch(void* const* d_in, const int* in_sizes, int n_in,
                              void* d_out, int out_size, void* d_ws, size_t ws_size,
                              hipStream_t stream) {
    const int*   lr_idx = (const int*)d_in[0];
    const int*   h1i    = (const int*)d_in[1];
    const int*   h2i    = (const int*)d_in[2];
    const int*   h3i    = (const int*)d_in[3];
    const float* lrf    = (const float*)d_in[4];
    const float* f1     = (const float*)d_in[5];
    const float* f2     = (const float*)d_in[6];
    const float* f3     = (const float*)d_in[7];
    const float* w14    = (const float*)d_in[8];
    const float* b14    = (const float*)d_in[9];
    const float* w24    = (const float*)d_in[10];
    const float* b24    = (const float*)d_in[11];
    const float* w34    = (const float*)d_in[12];
    const float* b34    = (const float*)d_in[13];
    const float* wout   = (const float*)d_in[14];
    const float* gam    = (const float*)d_in[15];
    const float* bet    = (const float*)d_in[16];
    const float* mean   = (const float*)d_in[17];
    const float* var    = (const float*)d_in[18];
    float* ws  = (float*)d_ws;
    float* out = (float*)d_out;

    if (ws_size < (size_t)WS_FLOATS * sizeof(float)) return;  // ~8.5 MB scratch

    // 32 hist blocks + 1833 flat blocks (F1 1024, F2 512, F3 256, BN 41)
    kprep<<<1865, 256, 0, stream>>>(lr_idx, h1i, h2i, h3i, f1, f2, f3,
                                    w14, b14, w24, b24, w34, b34,
                                    wout, gam, bet, mean, var, ws);
    ksort<<<NBLK, 1024, 0, stream>>>(lr_idx, h1i, h2i, h3i, ws);
    // 256 blocks x 512 thr: 32-pt groups, 3 sets + final matmul fused
    kmain<<<256, 512, 0, stream>>>(ws, lrf, h1i, h2i, h3i, w14, w24, w34, out);
}